// Round 6
// baseline (9430.487 us; speedup 1.0000x reference)
//
#include <hip/hip_runtime.h>
#include <stdint.h>

#define IN_DIM 256
#define HID 512
#define OUT_DIM 128
#define BT 64
#define NSTEPS 40
#define TPB 512  // 8 waves, 2/SIMD — the ONLY register-feasible geometry (R2-R5)

typedef float f32x4 __attribute__((ext_vector_type(4)));
typedef __bf16 bf16x8 __attribute__((ext_vector_type(8)));

// 2*log2(e): W,U,b are pre-scaled by this so tanh needs no mul/clamp.
#define TANH_SC 2.8853900817779268f

// Single-instruction bf16 pair pack (RNE). lo=bf16(a), hi=bf16(b).
static __device__ __forceinline__ uint32_t cvtpk(float a, float b) {
  uint32_t r;
  asm("v_cvt_pk_bf16_f32 %0, %1, %2" : "=v"(r) : "v"(a), "v"(b));
  return r;
}
static __device__ __forceinline__ float bflo(uint32_t u) {
  union { uint32_t u; float f; } v; v.u = u << 16; return v.f;
}
static __device__ __forceinline__ float bfhi(uint32_t u) {
  union { uint32_t u; float f; } v; v.u = u & 0xFFFF0000u; return v.f;
}
// fp16 pair pack/unpack — INTEGER-SCALAR ONLY (R7: __half2 struct unions
// defeat SROA -> whole state array lands in scratch).
static __device__ __forceinline__ uint32_t pkh(float a, float b) {
  const uint16_t lo = __builtin_bit_cast(uint16_t, (_Float16)a);
  const uint16_t hi = __builtin_bit_cast(uint16_t, (_Float16)b);
  return (uint32_t)lo | ((uint32_t)hi << 16);
}
static __device__ __forceinline__ float h2lo(uint32_t u) {
  return (float)__builtin_bit_cast(_Float16, (uint16_t)(u & 0xFFFFu));
}
static __device__ __forceinline__ float h2hi(uint32_t u) {
  return (float)__builtin_bit_cast(_Float16, (uint16_t)(u >> 16));
}
// tanh(x) = 1 - 2/(e^{2x}+1). Input PRE-SCALED by 2*log2(e) at pack time.
// No clamp: x>>0 -> exp2=inf -> rcp=0 -> 1; x<<0 -> exp2=0 -> -1.
static __device__ __forceinline__ float tanh_fast(float x) {
  const float e = __builtin_amdgcn_exp2f(x);
  return __builtin_fmaf(-2.0f, __builtin_amdgcn_rcpf(e + 1.0f), 1.0f);
}

// byte address of bf16 element (m=batch row, n=k/hidden col) in the swizzled
// 64x512 LDS tile. Row stride 1024 B; 16B chunks XOR-swizzled by (m&15).
static __device__ __forceinline__ int lds_ea(int m, int n) {
  return m * 1024 + ((((n >> 3) ^ (m & 15)) << 4)) + ((n & 7) << 1);
}

// Swapped-operand GEMM (accumulate-into): D[hidden][batch] += W * h^T.
// A = weight frags (packed global stream), B = h rows from LDS.
// Used for the two setup GEMMs where acc is pre-initialized with bias.
template <int NKSEG>
static __device__ __forceinline__ void mm_sw(const __bf16* __restrict__ Ap,
                                             const char* lds, int B1,
                                             f32x4 acc[4][4]) {
#pragma unroll 2
  for (int ks = 0; ks < NKSEG; ++ks) {
    const int ba = (B1 ^ ((ks & 3) << 6)) + ((ks >> 2) << 8);
    bf16x8 wf[4];
#pragma unroll
    for (int i = 0; i < 4; ++i)
      wf[i] = *(const bf16x8*)(Ap + (size_t)(i * NKSEG + ks) * 512);
#pragma unroll
    for (int j = 0; j < 4; ++j) {
      const bf16x8 hf = *(const bf16x8*)(lds + ba + j * 16384);
#pragma unroll
      for (int i = 0; i < 4; ++i)
        acc[i][j] = __builtin_amdgcn_mfma_f32_16x16x32_bf16(wf[i], hf,
                                                            acc[i][j], 0, 0, 0);
    }
  }
}

// R14: C-in variant for the RK4 W-GEMM. ks=0 is peeled and takes cin
// (= drive, resident in 64 AGPRs, READ-ONLY) as the MFMA C operand.
// This deletes the entire per-eval drive path: no LDS drive buffer, no
// unpack, no v_accvgpr acc-init — MFMA issues immediately after barrier.
template <int NKSEG>
static __device__ __forceinline__ void mm_sw_c(const __bf16* __restrict__ Ap,
                                               const char* lds, int B1,
                                               const f32x4 cin[4][4],
                                               f32x4 acc[4][4]) {
  {  // ks = 0: ba = B1
    bf16x8 wf[4];
#pragma unroll
    for (int i = 0; i < 4; ++i)
      wf[i] = *(const bf16x8*)(Ap + (size_t)(i * NKSEG) * 512);
#pragma unroll
    for (int j = 0; j < 4; ++j) {
      const bf16x8 hf = *(const bf16x8*)(lds + B1 + j * 16384);
#pragma unroll
      for (int i = 0; i < 4; ++i)
        acc[i][j] = __builtin_amdgcn_mfma_f32_16x16x32_bf16(wf[i], hf,
                                                            cin[i][j], 0, 0, 0);
    }
  }
#pragma unroll 2
  for (int ks = 1; ks < NKSEG; ++ks) {
    const int ba = (B1 ^ ((ks & 3) << 6)) + ((ks >> 2) << 8);
    bf16x8 wf[4];
#pragma unroll
    for (int i = 0; i < 4; ++i)
      wf[i] = *(const bf16x8*)(Ap + (size_t)(i * NKSEG + ks) * 512);
#pragma unroll
    for (int j = 0; j < 4; ++j) {
      const bf16x8 hf = *(const bf16x8*)(lds + ba + j * 16384);
#pragma unroll
      for (int i = 0; i < 4; ++i)
        acc[i][j] = __builtin_amdgcn_mfma_f32_16x16x32_bf16(wf[i], hf,
                                                            acc[i][j], 0, 0, 0);
    }
  }
}

__global__ __launch_bounds__(TPB, 2) void liq_main(
    const float* __restrict__ x, const float* __restrict__ bx,
    const float* __restrict__ bvec, const float* __restrict__ tau,
    const float* __restrict__ bfh, const __bf16* __restrict__ Wx_p,
    const __bf16* __restrict__ U_p, const __bf16* __restrict__ W_p,
    const __bf16* __restrict__ Wf_p, float* __restrict__ out) {
  // R14: drive LDS freed (drive -> AGPR C-in) => double-buffered operand
  // tile in the same 128 KB footprint: eval reads rb, writes h_tmp inline
  // to wb, ONE barrier per eval. Register budget: acc 64 + drv 64 AGPR,
  // VGPR ~R1's 120 (Sp bf16-packed for margin; validated R2/R3/R5).
  __shared__ __align__(16) char bufA[BT * 1024];  // 64 KB
  __shared__ __align__(16) char bufB[BT * 1024];  // 64 KB
  const int tid = threadIdx.x;
  const int w = tid >> 6;  // 8 waves; wave owns hidden [64w, 64w+64)
  const int lane = tid & 63;
  const int l15 = lane & 15;
  const int q = lane >> 4;
  const int row0 = blockIdx.x * BT;

  // B-frag read base: addr(ks,j) = (B1 ^ ((ks&3)<<6)) + (ks>>2)*256 + j*16384
  const int B1 =
      l15 * 1024 + ((q ^ (l15 & 3)) << 4) + (((l15 >> 2) & 3) << 6);
  // stage/readback base: addr(i,j) = (A0 ^ (i<<5)) + j*16384
  // (element: batch row 16j+l15, hidden cols 64w+16i+4q .. +3, b64)
  const int chunk0 = (((q >> 1) ^ (l15 & 1))) | (((l15 >> 1) & 3) << 1) |
                     ((8 * w) ^ (l15 & 8));
  const int A0 = l15 * 1024 + ((q & 1) << 3) + (chunk0 << 4);

  // ---- stage x tile (64 x 256 fp32 -> bf16) into bufA ----
  {
    const float4* x4 = (const float4*)(x + (size_t)row0 * IN_DIM);
#pragma unroll
    for (int it = 0; it < (BT * IN_DIM / 4) / TPB; ++it) {  // 8
      const int id = tid + it * TPB;
      const float4 v = x4[id];
      const int m = id >> 6;
      const int c = (id & 63) << 2;
      uint2 pk;
      pk.x = cvtpk(v.x, v.y);
      pk.y = cvtpk(v.z, v.w);
      *(uint2*)(bufA + lds_ea(m, c)) = pk;  // (c&7) in {0,4} -> 8B aligned
    }
  }

  // itau in fp32 regs (16 VGPR, as R1-measured)
  f32x4 it4[4];
#pragma unroll
  for (int i = 0; i < 4; ++i) {
    const float4 tv = *(const float4*)(tau + 64 * w + 16 * i + 4 * q);
    it4[i] = (f32x4){1.0f / tv.x, 1.0f / tv.y, 1.0f / tv.z, 1.0f / tv.w};
  }
  __syncthreads();

  // ---- u = x @ Wx^T + bx (reads bufA) ----
  f32x4 acc[4][4];
#pragma unroll
  for (int i = 0; i < 4; ++i) {
    const float4 b4 = *(const float4*)(bx + 64 * w + 16 * i + 4 * q);
#pragma unroll
    for (int j = 0; j < 4; ++j) acc[i][j] = (f32x4){b4.x, b4.y, b4.z, b4.w};
  }
  mm_sw<IN_DIM / 32>(Wx_p + (size_t)w * 16384 + lane * 8, bufA, B1, acc);

  uint32_t h16[32];  // h state, fp16 pairs (integer-packed, SROA-safe)
#pragma unroll
  for (int i = 0; i < 4; ++i)
#pragma unroll
    for (int j = 0; j < 4; ++j) {
      const int ti = i * 4 + j;
      h16[ti * 2] = pkh(acc[i][j][0], acc[i][j][1]);
      h16[ti * 2 + 1] = pkh(acc[i][j][2], acc[i][j][3]);
    }

  // stage u into bufB (fresh buffer: no barrier needed before these writes)
#pragma unroll
  for (int i = 0; i < 4; ++i)
#pragma unroll
    for (int j = 0; j < 4; ++j) {
      uint2 pk;
      pk.x = cvtpk(acc[i][j][0], acc[i][j][1]);
      pk.y = cvtpk(acc[i][j][2], acc[i][j][3]);
      *(uint2*)(bufB + ((A0 ^ (i << 5)) + j * 16384)) = pk;
    }
  __syncthreads();

  // ---- drive = u @ U^T + b (pre-scaled) -> PERMANENT f32 in AGPRs ----
  // drv is the MFMA C-in for every RK4 W-GEMM below; never modified.
  f32x4 drv[4][4];
#pragma unroll
  for (int i = 0; i < 4; ++i) {
    const float4 b4 = *(const float4*)(bvec + 64 * w + 16 * i + 4 * q);
#pragma unroll
    for (int j = 0; j < 4; ++j)
      drv[i][j] = (f32x4){b4.x * TANH_SC, b4.y * TANH_SC, b4.z * TANH_SC,
                          b4.w * TANH_SC};
  }
  mm_sw<HID / 32>(U_p + (size_t)w * 32768 + lane * 8, bufB, B1, drv);

  const float dt = 1.0f / NSTEPS;
  const float hdt = 0.5f * dt;
  const float dt6 = dt / 6.0f;
  uint32_t Sp[32];  // RK4 sum, bf16 pairs (validated R2/R3/R5, same absmax)
  const __bf16* Wp_base = W_p + (size_t)w * 32768 + lane * 8;

  const char* rb = bufB;  // read buffer (holds h operand for current eval)
  char* wb = bufA;        // write buffer (receives h_tmp for next eval)

  for (int st = 0; st < NSTEPS; ++st) {
    for (int e = 0; e < 4; ++e) {  // k1..k4 (rolled: I-cache)
      // W-GEMM with drive as C-in: no acc init, no drive unpack.
      mm_sw_c<HID / 32>(Wp_base, rb, B1, drv, acc);

      const float wk = (e == 1 || e == 2) ? 2.0f : 1.0f;
      const float cn = (e < 2) ? hdt : dt;
#pragma unroll
      for (int i = 0; i < 4; ++i)
#pragma unroll
        for (int j = 0; j < 4; ++j) {
          const int ti = i * 4 + j;
          const int sa = (A0 ^ (i << 5)) + j * 16384;
          const float hc0 = h2lo(h16[ti * 2]), hc1 = h2hi(h16[ti * 2]);
          const float hc2 = h2lo(h16[ti * 2 + 1]), hc3 = h2hi(h16[ti * 2 + 1]);
          float hin[4];
          if (e == 0) {
            hin[0] = hc0; hin[1] = hc1; hin[2] = hc2; hin[3] = hc3;
          } else {  // h_tmp (bf16) of previous sub-step from the read buffer
            const uint2 hb = *(const uint2*)(rb + sa);
            hin[0] = bflo(hb.x); hin[1] = bfhi(hb.x);
            hin[2] = bflo(hb.y); hin[3] = bfhi(hb.y);
          }
          float kk[4];
          kk[0] = (tanh_fast(acc[i][j][0]) - hin[0]) * it4[i][0];
          kk[1] = (tanh_fast(acc[i][j][1]) - hin[1]) * it4[i][1];
          kk[2] = (tanh_fast(acc[i][j][2]) - hin[2]) * it4[i][2];
          kk[3] = (tanh_fast(acc[i][j][3]) - hin[3]) * it4[i][3];
          float n0, n1, n2, n3;
          if (e == 0) {
            Sp[ti * 2] = cvtpk(kk[0], kk[1]);
            Sp[ti * 2 + 1] = cvtpk(kk[2], kk[3]);
            n0 = __builtin_fmaf(cn, kk[0], hc0);
            n1 = __builtin_fmaf(cn, kk[1], hc1);
            n2 = __builtin_fmaf(cn, kk[2], hc2);
            n3 = __builtin_fmaf(cn, kk[3], hc3);
          } else if (e < 3) {
            const float s0 = __builtin_fmaf(wk, kk[0], bflo(Sp[ti * 2]));
            const float s1 = __builtin_fmaf(wk, kk[1], bfhi(Sp[ti * 2]));
            const float s2 = __builtin_fmaf(wk, kk[2], bflo(Sp[ti * 2 + 1]));
            const float s3 = __builtin_fmaf(wk, kk[3], bfhi(Sp[ti * 2 + 1]));
            Sp[ti * 2] = cvtpk(s0, s1);
            Sp[ti * 2 + 1] = cvtpk(s2, s3);
            n0 = __builtin_fmaf(cn, kk[0], hc0);
            n1 = __builtin_fmaf(cn, kk[1], hc1);
            n2 = __builtin_fmaf(cn, kk[2], hc2);
            n3 = __builtin_fmaf(cn, kk[3], hc3);
          } else {  // e == 3: RK4 state update (fp16 RNE, integer-packed)
            n0 = __builtin_fmaf(dt6, bflo(Sp[ti * 2]) + kk[0], hc0);
            n1 = __builtin_fmaf(dt6, bfhi(Sp[ti * 2]) + kk[1], hc1);
            n2 = __builtin_fmaf(dt6, bflo(Sp[ti * 2 + 1]) + kk[2], hc2);
            n3 = __builtin_fmaf(dt6, bfhi(Sp[ti * 2 + 1]) + kk[3], hc3);
            h16[ti * 2] = pkh(n0, n1);
            h16[ti * 2 + 1] = pkh(n2, n3);
          }
          // inline h_tmp write to the WRITE buffer: no race with rb readers,
          // no acc staging round-trip (drops ~128 v_accvgpr moves/eval).
          uint2 pk;
          pk.x = cvtpk(n0, n1);
          pk.y = cvtpk(n2, n3);
          *(uint2*)(wb + sa) = pk;
        }
      __syncthreads();  // wb fully written & visible; rb reads drained
      const char* t = rb; rb = wb; wb = (char*)t;
    }
  }
  // 160 evals = 160 swaps (even) -> rb ends at the buffer holding h_T.

  // ---- head: out = h_T @ Wf^T + bf (A = Wf frags; wave w -> out cols 16w..) --
  {
    const float4 b4 = *(const float4*)(bfh + 16 * w + 4 * q);
    f32x4 a2[4];
#pragma unroll
    for (int j = 0; j < 4; ++j) a2[j] = (f32x4){b4.x, b4.y, b4.z, b4.w};
#pragma unroll 2
    for (int ks = 0; ks < HID / 32; ++ks) {
      const bf16x8 wf =
          *(const bf16x8*)(Wf_p + (size_t)(w * 16 + ks) * 512 + lane * 8);
      const int ba = (B1 ^ ((ks & 3) << 6)) + ((ks >> 2) << 8);
#pragma unroll
      for (int j = 0; j < 4; ++j) {
        const bf16x8 hf = *(const bf16x8*)(rb + ba + j * 16384);
        a2[j] = __builtin_amdgcn_mfma_f32_16x16x32_bf16(wf, hf, a2[j], 0, 0, 0);
      }
    }
#pragma unroll
    for (int j = 0; j < 4; ++j) {
      float4 o;
      o.x = a2[j][0]; o.y = a2[j][1]; o.z = a2[j][2]; o.w = a2[j][3];
      *(float4*)(out + (size_t)(row0 + 16 * j + l15) * OUT_DIM + 16 * w +
                 4 * q) = o;
    }
  }
}

// Pack row-major fp32 weight [N][K] into bf16 frag stream (16-row tiles):
// dst[((nt*KSEG+ks)*64+lane)*8+j] = scale*W[nt*16+(lane&15)][ks*32+(lane>>4)*8+j]
// scale: W and U carry 2*log2(e) so tanh_fast needs no multiply/clamp.
__global__ void pack_bfrag(const float* __restrict__ src, __bf16* __restrict__ dst,
                           int K, int kslog, int total, float scale) {
  const int i = blockIdx.x * blockDim.x + threadIdx.x;
  if (i >= total) return;
  const int j = i & 7;
  const int lane = (i >> 3) & 63;
  const int rem = i >> 9;
  const int ks = rem & ((1 << kslog) - 1);
  const int nt = rem >> kslog;
  const int n = (nt << 4) + (lane & 15);
  const int k = (ks << 5) + ((lane >> 4) << 3) + j;
  dst[i] = (__bf16)(src[n * K + k] * scale);
}

extern "C" void kernel_launch(void* const* d_in, const int* in_sizes, int n_in,
                              void* d_out, int out_size, void* d_ws, size_t ws_size,
                              hipStream_t stream) {
  const float* x = (const float*)d_in[0];
  const float* Wx = (const float*)d_in[1];
  const float* bx = (const float*)d_in[2];
  const float* W = (const float*)d_in[3];
  const float* U = (const float*)d_in[4];
  const float* b = (const float*)d_in[5];
  const float* tau = (const float*)d_in[6];
  const float* Wf = (const float*)d_in[7];
  const float* bf_ = (const float*)d_in[8];
  float* out = (float*)d_out;

  char* ws = (char*)d_ws;  // 1.375 MB used
  __bf16* W_p = (__bf16*)(ws + 0);
  __bf16* U_p = (__bf16*)(ws + (512 * 1024));
  __bf16* Wx_p = (__bf16*)(ws + (1024 * 1024));
  __bf16* Wf_p = (__bf16*)(ws + (1280 * 1024));

  pack_bfrag<<<(HID * HID) / 256, 256, 0, stream>>>(W, W_p, HID, 4, HID * HID,
                                                    TANH_SC);
  pack_bfrag<<<(HID * HID) / 256, 256, 0, stream>>>(U, U_p, HID, 4, HID * HID,
                                                    TANH_SC);
  pack_bfrag<<<(HID * IN_DIM) / 256, 256, 0, stream>>>(Wx, Wx_p, IN_DIM, 3,
                                                       HID * IN_DIM, 1.0f);
  pack_bfrag<<<(OUT_DIM * HID) / 256, 256, 0, stream>>>(Wf, Wf_p, HID, 4,
                                                        OUT_DIM * HID, 1.0f);

  liq_main<<<32768 / BT, TPB, 0, stream>>>(x, bx, b, tau, bf_, Wx_p, U_p, W_p,
                                           Wf_p, out);
}

// Round 7
// 3086.560 us; speedup vs baseline: 3.0553x; 3.0553x over previous
//
#include <hip/hip_runtime.h>
#include <stdint.h>

#define IN_DIM 256
#define HID 512
#define OUT_DIM 128
#define BT 64
#define NSTEPS 40
#define TPB 512  // 8 waves, 2/SIMD — the only register-feasible geometry (R2-R6)

typedef float f32x4 __attribute__((ext_vector_type(4)));
typedef __bf16 bf16x8 __attribute__((ext_vector_type(8)));

// 2*log2(e): W,U,b are pre-scaled by this so tanh needs no mul/clamp.
#define TANH_SC 2.8853900817779268f

// Single-instruction bf16 pair pack (RNE). lo=bf16(a), hi=bf16(b).
static __device__ __forceinline__ uint32_t cvtpk(float a, float b) {
  uint32_t r;
  asm("v_cvt_pk_bf16_f32 %0, %1, %2" : "=v"(r) : "v"(a), "v"(b));
  return r;
}
static __device__ __forceinline__ float bflo(uint32_t u) {
  union { uint32_t u; float f; } v; v.u = u << 16; return v.f;
}
static __device__ __forceinline__ float bfhi(uint32_t u) {
  union { uint32_t u; float f; } v; v.u = u & 0xFFFF0000u; return v.f;
}
// fp16 pair pack/unpack — INTEGER-SCALAR ONLY (R7: __half2 struct unions
// defeat SROA -> whole state array lands in scratch).
static __device__ __forceinline__ uint32_t pkh(float a, float b) {
  const uint16_t lo = __builtin_bit_cast(uint16_t, (_Float16)a);
  const uint16_t hi = __builtin_bit_cast(uint16_t, (_Float16)b);
  return (uint32_t)lo | ((uint32_t)hi << 16);
}
static __device__ __forceinline__ float h2lo(uint32_t u) {
  return (float)__builtin_bit_cast(_Float16, (uint16_t)(u & 0xFFFFu));
}
static __device__ __forceinline__ float h2hi(uint32_t u) {
  return (float)__builtin_bit_cast(_Float16, (uint16_t)(u >> 16));
}
// tanh(x) = 1 - 2/(e^{2x}+1). Input PRE-SCALED by 2*log2(e) at pack time.
// No clamp: x>>0 -> exp2=inf -> rcp=0 -> 1; x<<0 -> exp2=0 -> -1.
static __device__ __forceinline__ float tanh_fast(float x) {
  const float e = __builtin_amdgcn_exp2f(x);
  return __builtin_fmaf(-2.0f, __builtin_amdgcn_rcpf(e + 1.0f), 1.0f);
}

// byte address of bf16 element (m=batch row, n=k/hidden col) in the swizzled
// 64x512 LDS tile. Row stride 1024 B; 16B chunks XOR-swizzled by (m&15).
static __device__ __forceinline__ int lds_ea(int m, int n) {
  return m * 1024 + ((((n >> 3) ^ (m & 15)) << 4)) + ((n & 7) << 1);
}

// Swapped-operand GEMM: D[hidden][batch] += W * h^T.
// A = weight frags (packed global stream), B = h rows from LDS.
// 4 wf frags up front, one hf read feeds 4 MFMAs.
template <int NKSEG>
static __device__ __forceinline__ void mm_sw(const __bf16* __restrict__ Ap,
                                             const char* lds, int B1,
                                             f32x4 acc[4][4]) {
#pragma unroll 2
  for (int ks = 0; ks < NKSEG; ++ks) {
    const int ba = (B1 ^ ((ks & 3) << 6)) + ((ks >> 2) << 8);
    bf16x8 wf[4];
#pragma unroll
    for (int i = 0; i < 4; ++i)
      wf[i] = *(const bf16x8*)(Ap + (size_t)(i * NKSEG + ks) * 512);
#pragma unroll
    for (int j = 0; j < 4; ++j) {
      const bf16x8 hf = *(const bf16x8*)(lds + ba + j * 16384);
#pragma unroll
      for (int i = 0; i < 4; ++i)
        acc[i][j] = __builtin_amdgcn_mfma_f32_16x16x32_bf16(wf[i], hf,
                                                            acc[i][j], 0, 0, 0);
    }
  }
}

// ============================================================================
// R15 primary kernel: drive in GLOBAL workspace (L2-resident, own-write/
// own-read, coalesced dwordx4) -> the 64 KB of LDS it vacated becomes a
// double-buffered operand tile: eval reads rb, writes h inline to wb,
// ONE barrier per eval. Per-wave register profile = Round-1's verified
// no-spill split (acc 64 AGPR + ~120 VGPR incl. Sp f32): drive is
// transient-load-only, no new persistent state (the R4/R6 failure).
// ============================================================================
__global__ __launch_bounds__(TPB, 2) void liq_main_g(
    const float* __restrict__ x, const float* __restrict__ bx,
    const float* __restrict__ bvec, const float* __restrict__ tau,
    const float* __restrict__ bfh, const __bf16* __restrict__ Wx_p,
    const __bf16* __restrict__ U_p, const __bf16* __restrict__ W_p,
    const __bf16* __restrict__ Wf_p, char* __restrict__ drvg_base,
    float* __restrict__ out) {
  __shared__ __align__(16) char bufA[BT * 1024];  // 64 KB
  __shared__ __align__(16) char bufB[BT * 1024];  // 64 KB
  const int tid = threadIdx.x;
  const int w = tid >> 6;  // 8 waves; wave owns hidden [64w, 64w+64)
  const int lane = tid & 63;
  const int l15 = lane & 15;
  const int q = lane >> 4;
  const int row0 = blockIdx.x * BT;
  // per-block 64 KB drive region: 8 uint4 per thread, lane-contiguous 16B
  char* drvg = drvg_base + (size_t)blockIdx.x * 65536;

  // B-frag read base: addr(ks,j) = (B1 ^ ((ks&3)<<6)) + (ks>>2)*256 + j*16384
  const int B1 =
      l15 * 1024 + ((q ^ (l15 & 3)) << 4) + (((l15 >> 2) & 3) << 6);
  // stage/readback base: addr(i,j) = (A0 ^ (i<<5)) + j*16384
  // (element: batch row 16j+l15, hidden cols 64w+16i+4q .. +3, b64)
  const int chunk0 = (((q >> 1) ^ (l15 & 1))) | (((l15 >> 1) & 3) << 1) |
                     ((8 * w) ^ (l15 & 8));
  const int A0 = l15 * 1024 + ((q & 1) << 3) + (chunk0 << 4);

  // ---- stage x tile (64 x 256 fp32 -> bf16) into bufA ----
  {
    const float4* x4 = (const float4*)(x + (size_t)row0 * IN_DIM);
#pragma unroll
    for (int it = 0; it < (BT * IN_DIM / 4) / TPB; ++it) {  // 8
      const int id = tid + it * TPB;
      const float4 v = x4[id];
      const int m = id >> 6;
      const int c = (id & 63) << 2;
      uint2 pk;
      pk.x = cvtpk(v.x, v.y);
      pk.y = cvtpk(v.z, v.w);
      *(uint2*)(bufA + lds_ea(m, c)) = pk;  // (c&7) in {0,4} -> 8B aligned
    }
  }

  // itau in fp32 regs (16 VGPR, as Round-1)
  f32x4 it4[4];
#pragma unroll
  for (int i = 0; i < 4; ++i) {
    const float4 tv = *(const float4*)(tau + 64 * w + 16 * i + 4 * q);
    it4[i] = (f32x4){1.0f / tv.x, 1.0f / tv.y, 1.0f / tv.z, 1.0f / tv.w};
  }
  __syncthreads();  // x tile visible

  // ---- u = x @ Wx^T + bx (reads bufA) ----
  f32x4 acc[4][4];
#pragma unroll
  for (int i = 0; i < 4; ++i) {
    const float4 b4 = *(const float4*)(bx + 64 * w + 16 * i + 4 * q);
#pragma unroll
    for (int j = 0; j < 4; ++j) acc[i][j] = (f32x4){b4.x, b4.y, b4.z, b4.w};
  }
  mm_sw<IN_DIM / 32>(Wx_p + (size_t)w * 16384 + lane * 8, bufA, B1, acc);

  uint32_t h16[32];  // h state, fp16 pairs (integer-packed, SROA-safe)
#pragma unroll
  for (int i = 0; i < 4; ++i)
#pragma unroll
    for (int j = 0; j < 4; ++j) {
      const int ti = i * 4 + j;
      h16[ti * 2] = pkh(acc[i][j][0], acc[i][j][1]);
      h16[ti * 2 + 1] = pkh(acc[i][j][2], acc[i][j][3]);
    }

  // stage u into bufB (fresh buffer: no pre-write barrier needed)
#pragma unroll
  for (int i = 0; i < 4; ++i)
#pragma unroll
    for (int j = 0; j < 4; ++j) {
      uint2 pk;
      pk.x = cvtpk(acc[i][j][0], acc[i][j][1]);
      pk.y = cvtpk(acc[i][j][2], acc[i][j][3]);
      *(uint2*)(bufB + ((A0 ^ (i << 5)) + j * 16384)) = pk;
    }
  __syncthreads();  // u tile visible

  // ---- drive = u @ U^T + b (pre-scaled by TANH_SC) -> GLOBAL (bf16) ----
#pragma unroll
  for (int i = 0; i < 4; ++i) {
    const float4 b4 = *(const float4*)(bvec + 64 * w + 16 * i + 4 * q);
#pragma unroll
    for (int j = 0; j < 4; ++j)
      acc[i][j] = (f32x4){b4.x * TANH_SC, b4.y * TANH_SC, b4.z * TANH_SC,
                          b4.w * TANH_SC};
  }
  mm_sw<HID / 32>(U_p + (size_t)w * 32768 + lane * 8, bufB, B1, acc);
  // pair p covers ti=2p, 2p+1 (i=p>>1, j=2(p&1), 2(p&1)+1): 16B/thread/pair
#pragma unroll
  for (int p = 0; p < 8; ++p) {
    const int i = p >> 1;
    const int j0 = (p & 1) * 2;
    uint4 d4;
    d4.x = cvtpk(acc[i][j0][0], acc[i][j0][1]);
    d4.y = cvtpk(acc[i][j0][2], acc[i][j0][3]);
    d4.z = cvtpk(acc[i][j0 + 1][0], acc[i][j0 + 1][1]);
    d4.w = cvtpk(acc[i][j0 + 1][2], acc[i][j0 + 1][3]);
    *(uint4*)(drvg + (((p * TPB + tid)) << 4)) = d4;
  }
  __syncthreads();  // vmcnt(0) drain: drive stores complete before reloads

  const float dt = 1.0f / NSTEPS;
  const float hdt = 0.5f * dt;
  const float dt6 = dt / 6.0f;
  f32x4 Sp[16];  // RK4 sum in fp32 (Round-1's verified register profile)
  const __bf16* Wp_base = W_p + (size_t)w * 32768 + lane * 8;

  const char* rb = bufB;  // read buffer (h operand for current eval)
  char* wb = bufA;        // write buffer (receives h for next eval)

  for (int st = 0; st < NSTEPS; ++st) {
    for (int e = 0; e < 4; ++e) {  // k1..k4 (rolled: I-cache)
      // acc <- drive (global, L2-hit, coalesced dwordx4)
#pragma unroll
      for (int p = 0; p < 8; ++p) {
        const int i = p >> 1;
        const int j0 = (p & 1) * 2;
        const uint4 d4 = *(const uint4*)(drvg + (((p * TPB + tid)) << 4));
        acc[i][j0] = (f32x4){bflo(d4.x), bfhi(d4.x), bflo(d4.y), bfhi(d4.y)};
        acc[i][j0 + 1] =
            (f32x4){bflo(d4.z), bfhi(d4.z), bflo(d4.w), bfhi(d4.w)};
      }
      mm_sw<HID / 32>(Wp_base, rb, B1, acc);

      const float wk = (e == 1 || e == 2) ? 2.0f : 1.0f;
      const float cn = (e < 2) ? hdt : dt;
#pragma unroll
      for (int i = 0; i < 4; ++i)
#pragma unroll
        for (int j = 0; j < 4; ++j) {
          const int ti = i * 4 + j;
          const int sa = (A0 ^ (i << 5)) + j * 16384;
          const float hc0 = h2lo(h16[ti * 2]), hc1 = h2hi(h16[ti * 2]);
          const float hc2 = h2lo(h16[ti * 2 + 1]), hc3 = h2hi(h16[ti * 2 + 1]);
          float hin[4];
          if (e == 0) {
            hin[0] = hc0; hin[1] = hc1; hin[2] = hc2; hin[3] = hc3;
          } else {  // h_tmp (bf16) of previous sub-step from read buffer
            const uint2 hb = *(const uint2*)(rb + sa);
            hin[0] = bflo(hb.x); hin[1] = bfhi(hb.x);
            hin[2] = bflo(hb.y); hin[3] = bfhi(hb.y);
          }
          float kk[4];
          kk[0] = (tanh_fast(acc[i][j][0]) - hin[0]) * it4[i][0];
          kk[1] = (tanh_fast(acc[i][j][1]) - hin[1]) * it4[i][1];
          kk[2] = (tanh_fast(acc[i][j][2]) - hin[2]) * it4[i][2];
          kk[3] = (tanh_fast(acc[i][j][3]) - hin[3]) * it4[i][3];
          if (e == 0) {
            Sp[ti] = (f32x4){kk[0], kk[1], kk[2], kk[3]};
          } else if (e < 3) {
            Sp[ti][0] = __builtin_fmaf(wk, kk[0], Sp[ti][0]);
            Sp[ti][1] = __builtin_fmaf(wk, kk[1], Sp[ti][1]);
            Sp[ti][2] = __builtin_fmaf(wk, kk[2], Sp[ti][2]);
            Sp[ti][3] = __builtin_fmaf(wk, kk[3], Sp[ti][3]);
          }
          float n0, n1, n2, n3;
          if (e == 3) {  // RK4 state update (fp16 RNE, integer-packed)
            n0 = __builtin_fmaf(dt6, Sp[ti][0] + kk[0], hc0);
            n1 = __builtin_fmaf(dt6, Sp[ti][1] + kk[1], hc1);
            n2 = __builtin_fmaf(dt6, Sp[ti][2] + kk[2], hc2);
            n3 = __builtin_fmaf(dt6, Sp[ti][3] + kk[3], hc3);
            h16[ti * 2] = pkh(n0, n1);
            h16[ti * 2 + 1] = pkh(n2, n3);
          } else {
            n0 = __builtin_fmaf(cn, kk[0], hc0);
            n1 = __builtin_fmaf(cn, kk[1], hc1);
            n2 = __builtin_fmaf(cn, kk[2], hc2);
            n3 = __builtin_fmaf(cn, kk[3], hc3);
          }
          // inline h write to the WRITE buffer: no race with rb readers,
          // no acc/AGPR staging round-trip, no pre-write barrier.
          uint2 pk;
          pk.x = cvtpk(n0, n1);
          pk.y = cvtpk(n2, n3);
          *(uint2*)(wb + sa) = pk;
        }
      __syncthreads();  // wb visible; rb reads drained — ONE barrier/eval
      const char* t = rb; rb = wb; wb = (char*)t;
    }
  }

  // ---- head: out = h_T @ Wf^T + bf (rb holds h_T after even swap count) ----
  {
    const float4 b4 = *(const float4*)(bfh + 16 * w + 4 * q);
    f32x4 a2[4];
#pragma unroll
    for (int j = 0; j < 4; ++j) a2[j] = (f32x4){b4.x, b4.y, b4.z, b4.w};
#pragma unroll 2
    for (int ks = 0; ks < HID / 32; ++ks) {
      const bf16x8 wf =
          *(const bf16x8*)(Wf_p + (size_t)(w * 16 + ks) * 512 + lane * 8);
      const int ba = (B1 ^ ((ks & 3) << 6)) + ((ks >> 2) << 8);
#pragma unroll
      for (int j = 0; j < 4; ++j) {
        const bf16x8 hf = *(const bf16x8*)(rb + ba + j * 16384);
        a2[j] = __builtin_amdgcn_mfma_f32_16x16x32_bf16(wf, hf, a2[j], 0, 0, 0);
      }
    }
#pragma unroll
    for (int j = 0; j < 4; ++j) {
      float4 o;
      o.x = a2[j][0]; o.y = a2[j][1]; o.z = a2[j][2]; o.w = a2[j][3];
      *(float4*)(out + (size_t)(row0 + 16 * j + l15) * OUT_DIM + 16 * w +
                 4 * q) = o;
    }
  }
}

// ============================================================================
// Fallback kernel: Round-1 verbatim (verified 2965 us, no spill) — used when
// ws_size cannot host the 32 MB global drive buffer.
// ============================================================================
__global__ __launch_bounds__(TPB, 2) void liq_main_l(
    const float* __restrict__ x, const float* __restrict__ bx,
    const float* __restrict__ bvec, const float* __restrict__ tau,
    const float* __restrict__ bfh, const __bf16* __restrict__ Wx_p,
    const __bf16* __restrict__ U_p, const __bf16* __restrict__ W_p,
    const __bf16* __restrict__ Wf_p, float* __restrict__ out) {
  __shared__ __align__(16) char abuf[BT * 1024];  // 64 KB operand buffer
  __shared__ __align__(8) uint2 drv[16 * TPB];    // 64 KB drive (bf16 pairs)
  const int tid = threadIdx.x;
  const int w = tid >> 6;
  const int lane = tid & 63;
  const int l15 = lane & 15;
  const int q = lane >> 4;
  const int row0 = blockIdx.x * BT;

  const int B1 =
      l15 * 1024 + ((q ^ (l15 & 3)) << 4) + (((l15 >> 2) & 3) << 6);
  const int chunk0 = (((q >> 1) ^ (l15 & 1))) | (((l15 >> 1) & 3) << 1) |
                     ((8 * w) ^ (l15 & 8));
  const int A0 = l15 * 1024 + ((q & 1) << 3) + (chunk0 << 4);

  {
    const float4* x4 = (const float4*)(x + (size_t)row0 * IN_DIM);
#pragma unroll
    for (int it = 0; it < (BT * IN_DIM / 4) / TPB; ++it) {
      const int id = tid + it * TPB;
      const float4 v = x4[id];
      const int m = id >> 6;
      const int c = (id & 63) << 2;
      uint2 pk;
      pk.x = cvtpk(v.x, v.y);
      pk.y = cvtpk(v.z, v.w);
      *(uint2*)(abuf + lds_ea(m, c)) = pk;
    }
  }

  f32x4 it4[4];
#pragma unroll
  for (int i = 0; i < 4; ++i) {
    const float4 tv = *(const float4*)(tau + 64 * w + 16 * i + 4 * q);
    it4[i] = (f32x4){1.0f / tv.x, 1.0f / tv.y, 1.0f / tv.z, 1.0f / tv.w};
  }
  __syncthreads();

  f32x4 acc[4][4];
#pragma unroll
  for (int i = 0; i < 4; ++i) {
    const float4 b4 = *(const float4*)(bx + 64 * w + 16 * i + 4 * q);
#pragma unroll
    for (int j = 0; j < 4; ++j) acc[i][j] = (f32x4){b4.x, b4.y, b4.z, b4.w};
  }
  mm_sw<IN_DIM / 32>(Wx_p + (size_t)w * 16384 + lane * 8, abuf, B1, acc);

  uint32_t h16[32];
#pragma unroll
  for (int i = 0; i < 4; ++i)
#pragma unroll
    for (int j = 0; j < 4; ++j) {
      const int ti = i * 4 + j;
      h16[ti * 2] = pkh(acc[i][j][0], acc[i][j][1]);
      h16[ti * 2 + 1] = pkh(acc[i][j][2], acc[i][j][3]);
    }

  __syncthreads();
#pragma unroll
  for (int i = 0; i < 4; ++i)
#pragma unroll
    for (int j = 0; j < 4; ++j) {
      uint2 pk;
      pk.x = cvtpk(acc[i][j][0], acc[i][j][1]);
      pk.y = cvtpk(acc[i][j][2], acc[i][j][3]);
      *(uint2*)(abuf + ((A0 ^ (i << 5)) + j * 16384)) = pk;
    }
  __syncthreads();

#pragma unroll
  for (int i = 0; i < 4; ++i) {
    const float4 b4 = *(const float4*)(bvec + 64 * w + 16 * i + 4 * q);
#pragma unroll
    for (int j = 0; j < 4; ++j)
      acc[i][j] = (f32x4){b4.x * TANH_SC, b4.y * TANH_SC, b4.z * TANH_SC,
                          b4.w * TANH_SC};
  }
  mm_sw<HID / 32>(U_p + (size_t)w * 32768 + lane * 8, abuf, B1, acc);
#pragma unroll
  for (int i = 0; i < 4; ++i)
#pragma unroll
    for (int j = 0; j < 4; ++j) {
      uint2 pk;
      pk.x = cvtpk(acc[i][j][0], acc[i][j][1]);
      pk.y = cvtpk(acc[i][j][2], acc[i][j][3]);
      drv[(i * 4 + j) * TPB + tid] = pk;
    }

  const float dt = 1.0f / NSTEPS;
  const float hdt = 0.5f * dt;
  const float dt6 = dt / 6.0f;
  f32x4 Sp[16];
  const __bf16* Wp_base = W_p + (size_t)w * 32768 + lane * 8;

  for (int st = 0; st < NSTEPS; ++st) {
    for (int e = 0; e < 4; ++e) {
#pragma unroll
      for (int i = 0; i < 4; ++i)
#pragma unroll
        for (int j = 0; j < 4; ++j) {
          const uint2 d = drv[(i * 4 + j) * TPB + tid];
          acc[i][j] = (f32x4){bflo(d.x), bfhi(d.x), bflo(d.y), bfhi(d.y)};
        }
      mm_sw<HID / 32>(Wp_base, abuf, B1, acc);

      const float wk = (e == 1 || e == 2) ? 2.0f : 1.0f;
      const float cn = (e < 2) ? hdt : dt;
#pragma unroll
      for (int i = 0; i < 4; ++i)
#pragma unroll
        for (int j = 0; j < 4; ++j) {
          const int ti = i * 4 + j;
          const int sa = (A0 ^ (i << 5)) + j * 16384;
          const float hc0 = h2lo(h16[ti * 2]), hc1 = h2hi(h16[ti * 2]);
          const float hc2 = h2lo(h16[ti * 2 + 1]), hc3 = h2hi(h16[ti * 2 + 1]);
          float hin[4];
          if (e == 0) {
            hin[0] = hc0; hin[1] = hc1; hin[2] = hc2; hin[3] = hc3;
          } else {
            const uint2 hb = *(const uint2*)(abuf + sa);
            hin[0] = bflo(hb.x); hin[1] = bfhi(hb.x);
            hin[2] = bflo(hb.y); hin[3] = bfhi(hb.y);
          }
          float kk[4];
          kk[0] = (tanh_fast(acc[i][j][0]) - hin[0]) * it4[i][0];
          kk[1] = (tanh_fast(acc[i][j][1]) - hin[1]) * it4[i][1];
          kk[2] = (tanh_fast(acc[i][j][2]) - hin[2]) * it4[i][2];
          kk[3] = (tanh_fast(acc[i][j][3]) - hin[3]) * it4[i][3];
          if (e == 0) {
            Sp[ti] = (f32x4){kk[0], kk[1], kk[2], kk[3]};
          } else if (e < 3) {
            Sp[ti][0] = __builtin_fmaf(wk, kk[0], Sp[ti][0]);
            Sp[ti][1] = __builtin_fmaf(wk, kk[1], Sp[ti][1]);
            Sp[ti][2] = __builtin_fmaf(wk, kk[2], Sp[ti][2]);
            Sp[ti][3] = __builtin_fmaf(wk, kk[3], Sp[ti][3]);
          }
          float n0, n1, n2, n3;
          if (e == 3) {
            n0 = __builtin_fmaf(dt6, Sp[ti][0] + kk[0], hc0);
            n1 = __builtin_fmaf(dt6, Sp[ti][1] + kk[1], hc1);
            n2 = __builtin_fmaf(dt6, Sp[ti][2] + kk[2], hc2);
            n3 = __builtin_fmaf(dt6, Sp[ti][3] + kk[3], hc3);
            h16[ti * 2] = pkh(n0, n1);
            h16[ti * 2 + 1] = pkh(n2, n3);
          } else {
            n0 = __builtin_fmaf(cn, kk[0], hc0);
            n1 = __builtin_fmaf(cn, kk[1], hc1);
            n2 = __builtin_fmaf(cn, kk[2], hc2);
            n3 = __builtin_fmaf(cn, kk[3], hc3);
          }
          acc[i][j][0] = n0; acc[i][j][1] = n1;
          acc[i][j][2] = n2; acc[i][j][3] = n3;
        }
      __syncthreads();
#pragma unroll
      for (int i = 0; i < 4; ++i)
#pragma unroll
        for (int j = 0; j < 4; ++j) {
          uint2 pk;
          pk.x = cvtpk(acc[i][j][0], acc[i][j][1]);
          pk.y = cvtpk(acc[i][j][2], acc[i][j][3]);
          *(uint2*)(abuf + ((A0 ^ (i << 5)) + j * 16384)) = pk;
        }
      __syncthreads();
    }
  }

  {
    const float4 b4 = *(const float4*)(bfh + 16 * w + 4 * q);
    f32x4 a2[4];
#pragma unroll
    for (int j = 0; j < 4; ++j) a2[j] = (f32x4){b4.x, b4.y, b4.z, b4.w};
#pragma unroll 2
    for (int ks = 0; ks < HID / 32; ++ks) {
      const bf16x8 wf =
          *(const bf16x8*)(Wf_p + (size_t)(w * 16 + ks) * 512 + lane * 8);
      const int ba = (B1 ^ ((ks & 3) << 6)) + ((ks >> 2) << 8);
#pragma unroll
      for (int j = 0; j < 4; ++j) {
        const bf16x8 hf = *(const bf16x8*)(abuf + ba + j * 16384);
        a2[j] = __builtin_amdgcn_mfma_f32_16x16x32_bf16(wf, hf, a2[j], 0, 0, 0);
      }
    }
#pragma unroll
    for (int j = 0; j < 4; ++j) {
      float4 o;
      o.x = a2[j][0]; o.y = a2[j][1]; o.z = a2[j][2]; o.w = a2[j][3];
      *(float4*)(out + (size_t)(row0 + 16 * j + l15) * OUT_DIM + 16 * w +
                 4 * q) = o;
    }
  }
}

// Pack row-major fp32 weight [N][K] into bf16 frag stream (16-row tiles):
// dst[((nt*KSEG+ks)*64+lane)*8+j] = scale*W[nt*16+(lane&15)][ks*32+(lane>>4)*8+j]
// scale: W and U carry 2*log2(e) so tanh_fast needs no multiply/clamp.
__global__ void pack_bfrag(const float* __restrict__ src, __bf16* __restrict__ dst,
                           int K, int kslog, int total, float scale) {
  const int i = blockIdx.x * blockDim.x + threadIdx.x;
  if (i >= total) return;
  const int j = i & 7;
  const int lane = (i >> 3) & 63;
  const int rem = i >> 9;
  const int ks = rem & ((1 << kslog) - 1);
  const int nt = rem >> kslog;
  const int n = (nt << 4) + (lane & 15);
  const int k = (ks << 5) + ((lane >> 4) << 3) + j;
  dst[i] = (__bf16)(src[n * K + k] * scale);
}

extern "C" void kernel_launch(void* const* d_in, const int* in_sizes, int n_in,
                              void* d_out, int out_size, void* d_ws, size_t ws_size,
                              hipStream_t stream) {
  const float* x = (const float*)d_in[0];
  const float* Wx = (const float*)d_in[1];
  const float* bx = (const float*)d_in[2];
  const float* W = (const float*)d_in[3];
  const float* U = (const float*)d_in[4];
  const float* b = (const float*)d_in[5];
  const float* tau = (const float*)d_in[6];
  const float* Wf = (const float*)d_in[7];
  const float* bf_ = (const float*)d_in[8];
  float* out = (float*)d_out;

  char* ws = (char*)d_ws;
  __bf16* W_p = (__bf16*)(ws + 0);
  __bf16* U_p = (__bf16*)(ws + (512 * 1024));
  __bf16* Wx_p = (__bf16*)(ws + (1024 * 1024));
  __bf16* Wf_p = (__bf16*)(ws + (1280 * 1024));
  char* drvg = ws + (2u << 20);  // 32 MB drive buffer (512 blocks x 64 KB)
  const size_t need = (2u << 20) + (size_t)(32768 / BT) * 65536;

  pack_bfrag<<<(HID * HID) / 256, 256, 0, stream>>>(W, W_p, HID, 4, HID * HID,
                                                    TANH_SC);
  pack_bfrag<<<(HID * HID) / 256, 256, 0, stream>>>(U, U_p, HID, 4, HID * HID,
                                                    TANH_SC);
  pack_bfrag<<<(HID * IN_DIM) / 256, 256, 0, stream>>>(Wx, Wx_p, IN_DIM, 3,
                                                       HID * IN_DIM, 1.0f);
  pack_bfrag<<<(OUT_DIM * HID) / 256, 256, 0, stream>>>(Wf, Wf_p, HID, 4,
                                                        OUT_DIM * HID, 1.0f);

  if (ws_size >= need) {
    liq_main_g<<<32768 / BT, TPB, 0, stream>>>(x, bx, b, tau, bf_, Wx_p, U_p,
                                               W_p, Wf_p, drvg, out);
  } else {
    liq_main_l<<<32768 / BT, TPB, 0, stream>>>(x, bx, b, tau, bf_, Wx_p, U_p,
                                               W_p, Wf_p, out);
  }
}